// Round 6
// baseline (1403.289 us; speedup 1.0000x reference)
//
#include <hip/hip_runtime.h>
#include <hip/hip_bf16.h>
#include <hip/hip_cooperative_groups.h>

namespace cg = cooperative_groups;

typedef __hip_bfloat16 bf16;
typedef __attribute__((ext_vector_type(8))) short short8;
typedef __attribute__((ext_vector_type(4))) float f32x4;

#define N_NODES 50000
#define N_EDGES 1600000
#define FIN 8
#define HD 64
#define NH (N_NODES * HD)
#define NLAYERS 3
#define XSTRIDE 50048            // per-XCC array stride (64B-aligned)
#define CSR_BLOCKS 512

__device__ __forceinline__ float b2f(bf16 v) { return __bfloat162float(v); }
__device__ __forceinline__ float bu2f(unsigned int u) { return __uint_as_float(u << 16); }
__device__ __forceinline__ unsigned short f2bu(float f) {
    unsigned int x = __float_as_uint(f);
    unsigned int r = x + 0x7FFFu + ((x >> 16) & 1u);
    return (unsigned short)(r >> 16);
}

// ---------------- dtype detection ----------------
__global__ void k_detect(const void* __restrict__ ew, int* __restrict__ flag) {
    int ok = 1;
    for (int i = threadIdx.x; i < 512; i += 64) {
        float v = b2f(((const bf16*)ew)[i]);
        if (!(v >= 0.f && v <= 1.f)) ok = 0;
    }
    unsigned long long m = __ballot(ok);
    if (threadIdx.x == 0) *flag = (m == 0xFFFFFFFFFFFFFFFFull) ? 0 : 1;
}

struct ConvArgs {
    const void* src[14];
    float* dst[14];
    int cum[15];
};

__global__ void k_conv_small(ConvArgs a, const int* __restrict__ flag) {
    int q = blockIdx.x * 256 + threadIdx.x;
    if (q >= a.cum[14]) return;
    int s = 0;
    while (q >= a.cum[s + 1]) ++s;
    int off = q - a.cum[s];
    if (*flag) a.dst[s][off] = ((const float*)a.src[s])[off];
    else       a.dst[s][off] = bu2f(((const unsigned short*)a.src[s])[off]);
}

// ---------------- cooperative CSR build: all atomics + scatters XCD-local ----------------
// phase1: per-XCC count/deg histograms. phase2: totals, dis, scan, per-XCC bases.
// phase3: placement via per-XCC base counters -> per-row [xcc0|xcc1|...] fragments,
// contiguous per row in global CSR order.
__global__ void __launch_bounds__(256, 4) k_csr(
    const int* __restrict__ ei, const void* __restrict__ ewr,
    const int* __restrict__ flag,
    int* __restrict__ cnt8, float* __restrict__ deg8,     // 8*XSTRIDE each, pre-zeroed
    int* __restrict__ cnt, float* __restrict__ dis,       // N
    int* __restrict__ row_ptr,                            // N+1
    int* __restrict__ base8,                              // 8*XSTRIDE
    unsigned int* __restrict__ pairs4, int2* __restrict__ pairs8) {
    cg::grid_group grid = cg::this_grid();
    // HW_REG_XCC_ID = 20, offset 0, size 32 -> imm = 20 | (31<<11) = 63508
    int x = (int)(__builtin_amdgcn_s_getreg(63508) & 7u);
    int gtid = blockIdx.x * 256 + threadIdx.x;
    const int T = CSR_BLOCKS * 256;
    int f32 = *flag;
    const float* ewf = (const float*)ewr;
    const unsigned short* ewb = (const unsigned short*)ewr;

    // phase 1: histograms (XCC-private -> XCD-local atomic lines)
    for (int e = gtid; e < N_EDGES; e += T) {
        int r = ei[e], c = ei[N_EDGES + e];
        float w = f32 ? ewf[e] : bu2f(ewb[e]);
        atomicAdd(&cnt8[x * XSTRIDE + r], 1);
        atomicAdd(&deg8[x * XSTRIDE + c], w);
    }
    grid.sync();

    // phase 2a: totals + per-node XCC prefix (without row_ptr) + dis
    for (int n = gtid; n < N_NODES; n += T) {
        int run = 0;
        float d = 0.f;
#pragma unroll
        for (int xx = 0; xx < 8; ++xx) {
            base8[xx * XSTRIDE + n] = run;
            run += cnt8[xx * XSTRIDE + n];
            d += deg8[xx * XSTRIDE + n];
        }
        cnt[n] = run;
        dis[n] = fminf(rsqrtf(d), 1e6f);   // rsqrt(0)=inf -> 1e6, matches ref clamp
    }
    grid.sync();

    // phase 2b: exclusive scan of cnt -> row_ptr (block 0 only)
    if (blockIdx.x == 0) {
        __shared__ int part[256];
        int t = threadIdx.x;
        const int CH = 196;  // 256*196 = 50176 >= 50001
        int base = t * CH;
        int s = 0;
        for (int i = 0; i < CH; ++i) {
            int idx = base + i;
            if (idx < N_NODES) s += cnt[idx];
        }
        part[t] = s;
        __syncthreads();
        int val = s;
        for (int off = 1; off < 256; off <<= 1) {
            int other = (t >= off) ? part[t - off] : 0;
            __syncthreads();
            val += other;
            part[t] = val;
            __syncthreads();
        }
        int run = val - s;
        for (int i = 0; i < CH; ++i) {
            int idx = base + i;
            if (idx <= N_NODES) row_ptr[idx] = run;
            if (idx < N_NODES) run += cnt[idx];
        }
    }
    grid.sync();

    // phase 2c: base8 += row_ptr
    for (int n = gtid; n < N_NODES; n += T) {
        int rp = row_ptr[n];
#pragma unroll
        for (int xx = 0; xx < 8; ++xx) base8[xx * XSTRIDE + n] += rp;
    }
    grid.sync();

    // phase 3: placement (atomic bump on XCC-private base; writes land in
    // this XCD's fragment of each row -> minimal cross-XCD line sharing)
    for (int e = gtid; e < N_EDGES; e += T) {
        int r = ei[e], c = ei[N_EDGES + e];
        float w = f32 ? ewf[e] : bu2f(ewb[e]);
        float nrm = dis[r] * w * dis[c];
        int pos = atomicAdd(&base8[x * XSTRIDE + r], 1);
        pairs4[pos] = ((unsigned)c << 16) | (unsigned)f2bu(nrm);
        int2 p8;
        p8.x = c | (r << 16);
        p8.y = e;
        pairs8[pos] = p8;
    }
}

// ---------------- input projection (reads raw x with dtype flag) ----------------

__global__ void k_inproj(const void* __restrict__ xr_, const float* __restrict__ W,
                         const float* __restrict__ b, float* __restrict__ h,
                         unsigned short* __restrict__ h_bf, const int* __restrict__ flag) {
    __shared__ float Wt[FIN * HD];
    __shared__ float bs[HD];
    int t = threadIdx.x;
    int f32 = *flag;
    for (int idx = t; idx < FIN * HD; idx += 256) {
        int f = idx >> 3, j = idx & 7;
        Wt[j * 64 + f] = W[idx];
    }
    if (t < 64) bs[t] = b[t];
    __syncthreads();
    int gid = blockIdx.x * 256 + t;
    if (gid < NH) {
        int i = gid >> 6, f = gid & 63;
        const float* xf = (const float*)xr_ + i * FIN;
        const unsigned short* xb = (const unsigned short*)xr_ + i * FIN;
        float acc = bs[f];
#pragma unroll
        for (int j = 0; j < FIN; ++j) {
            float xv = f32 ? xf[j] : bu2f(xb[j]);
            acc += xv * Wt[j * 64 + f];
        }
        h[gid] = acc;
        h_bf[gid] = f2bu(acc);
    }
}

// ---------------- stats + coefficient MLP ----------------

__global__ void k_stats(const float* __restrict__ h, float* __restrict__ stats) {
    __shared__ float ssum[256], ssq[256];
    int t = threadIdx.x;
    float ls = 0.f, lq = 0.f;
    for (int idx = blockIdx.x * 256 + t; idx < NH; idx += 102400) {
        float v = h[idx];
        ls += v; lq += v * v;
    }
    ssum[t] = ls; ssq[t] = lq;
    __syncthreads();
    if (t < 64) {
        float a = ssum[t] + ssum[t + 64] + ssum[t + 128] + ssum[t + 192];
        atomicAdd(&stats[t], a);
        float q = ssq[t] + ssq[t + 64] + ssq[t + 128] + ssq[t + 192];
        for (int off = 32; off; off >>= 1) q += __shfl_down(q, off, 64);
        if (t == 0) atomicAdd(&stats[64], q);
    }
}

__global__ void k_coeffs(const float* __restrict__ stats,
                         const float* __restrict__ W1, const float* __restrict__ b1,
                         const float* __restrict__ W2, const float* __restrict__ b2,
                         int layer, float* __restrict__ coeffs) {
    __shared__ float ci[68];
    __shared__ float hid[32];
    __shared__ float lg[6];
    int t = threadIdx.x;
    float sf = stats[t];
    float tot = sf;
    for (int off = 1; off < 64; off <<= 1) tot += __shfl_xor(tot, off, 64);
    ci[t] = sf / (float)N_NODES;
    if (t == 0) {
        float sumsq = stats[64];
        float mean = tot / (float)NH;
        float var = (sumsq - (float)NH * mean * mean) / (float)(NH - 1);
        ci[64] = mean;
        ci[65] = sqrtf(fmaxf(var, 0.f));
        ci[66] = (float)N_NODES;
        ci[67] = (float)N_EDGES;
    }
    __syncthreads();
    if (t < 32) {
        float a = b1[layer * 32 + t];
        const float* wr = W1 + (layer * 32 + t) * 68;
        for (int j = 0; j < 68; ++j) a += ci[j] * wr[j];
        hid[t] = fmaxf(a, 0.f);
    }
    __syncthreads();
    if (t < 6) {
        float a = b2[layer * 6 + t];
        const float* wr = W2 + (layer * 6 + t) * 32;
        for (int g = 0; g < 32; ++g) a += hid[g] * wr[g];
        lg[t] = a;
    }
    __syncthreads();
    if (t == 0) {
        float mx = lg[0];
        for (int p = 1; p < 6; ++p) mx = fmaxf(mx, lg[p]);
        float s = 0.f, e[6];
        for (int p = 0; p < 6; ++p) { e[p] = expf(lg[p] - mx); s += e[p]; }
        for (int p = 0; p < 6; ++p) coeffs[p] = e[p] / s;
    }
}

// ---------------- SpMM hop: wave per node, lane = feature, 4 B/edge ----------------

__global__ void __launch_bounds__(256) k_spmm(
    const unsigned short* __restrict__ txo, unsigned short* __restrict__ txn,
    const int* __restrict__ row_ptr, const unsigned int* __restrict__ pairs4) {
    int lane = threadIdx.x & 63;
    int wv = __builtin_amdgcn_readfirstlane((int)(blockIdx.x * 4 + (threadIdx.x >> 6)));
    int s = __builtin_amdgcn_readfirstlane(row_ptr[wv]);
    int e = __builtin_amdgcn_readfirstlane(row_ptr[wv + 1]);
    float acc = 0.f;
    int j = s;
    for (; j + 7 < e; j += 8) {
        unsigned p0 = pairs4[j],     p1 = pairs4[j + 1], p2 = pairs4[j + 2], p3 = pairs4[j + 3];
        unsigned p4 = pairs4[j + 4], p5 = pairs4[j + 5], p6 = pairs4[j + 6], p7 = pairs4[j + 7];
        float g0 = bu2f(txo[(p0 >> 16) * 64 + lane]);
        float g1 = bu2f(txo[(p1 >> 16) * 64 + lane]);
        float g2 = bu2f(txo[(p2 >> 16) * 64 + lane]);
        float g3 = bu2f(txo[(p3 >> 16) * 64 + lane]);
        float g4 = bu2f(txo[(p4 >> 16) * 64 + lane]);
        float g5 = bu2f(txo[(p5 >> 16) * 64 + lane]);
        float g6 = bu2f(txo[(p6 >> 16) * 64 + lane]);
        float g7 = bu2f(txo[(p7 >> 16) * 64 + lane]);
        acc += bu2f(p0 & 0xFFFFu) * g0 + bu2f(p1 & 0xFFFFu) * g1 +
               bu2f(p2 & 0xFFFFu) * g2 + bu2f(p3 & 0xFFFFu) * g3;
        acc += bu2f(p4 & 0xFFFFu) * g4 + bu2f(p5 & 0xFFFFu) * g5 +
               bu2f(p6 & 0xFFFFu) * g6 + bu2f(p7 & 0xFFFFu) * g7;
    }
    for (; j < e; ++j) {
        unsigned p = pairs4[j];
        acc += bu2f(p & 0xFFFFu) * bu2f(txo[(p >> 16) * 64 + lane]);
    }
    txn[wv * 64 + lane] = f2bu(acc);
}

// ---------------- fused last hop + polynomial combine + layernorm ----------------

__global__ void __launch_bounds__(256) k_spmm_ln(
    const unsigned short* __restrict__ txo,
    const int* __restrict__ row_ptr, const unsigned int* __restrict__ pairs4,
    float* __restrict__ h, unsigned short* __restrict__ h_bf,
    const unsigned short* __restrict__ t1, const unsigned short* __restrict__ t2,
    const unsigned short* __restrict__ t3, const unsigned short* __restrict__ t4,
    const float* __restrict__ coeffs,
    const float* __restrict__ sc, const float* __restrict__ bi,
    int layer, int last, void* __restrict__ outv, const int* __restrict__ flag) {
    int lane = threadIdx.x & 63;
    int wv = __builtin_amdgcn_readfirstlane((int)(blockIdx.x * 4 + (threadIdx.x >> 6)));
    int s = __builtin_amdgcn_readfirstlane(row_ptr[wv]);
    int e = __builtin_amdgcn_readfirstlane(row_ptr[wv + 1]);
    float acc = 0.f;
    int j = s;
    for (; j + 7 < e; j += 8) {
        unsigned p0 = pairs4[j],     p1 = pairs4[j + 1], p2 = pairs4[j + 2], p3 = pairs4[j + 3];
        unsigned p4 = pairs4[j + 4], p5 = pairs4[j + 5], p6 = pairs4[j + 6], p7 = pairs4[j + 7];
        float g0 = bu2f(txo[(p0 >> 16) * 64 + lane]);
        float g1 = bu2f(txo[(p1 >> 16) * 64 + lane]);
        float g2 = bu2f(txo[(p2 >> 16) * 64 + lane]);
        float g3 = bu2f(txo[(p3 >> 16) * 64 + lane]);
        float g4 = bu2f(txo[(p4 >> 16) * 64 + lane]);
        float g5 = bu2f(txo[(p5 >> 16) * 64 + lane]);
        float g6 = bu2f(txo[(p6 >> 16) * 64 + lane]);
        float g7 = bu2f(txo[(p7 >> 16) * 64 + lane]);
        acc += bu2f(p0 & 0xFFFFu) * g0 + bu2f(p1 & 0xFFFFu) * g1 +
               bu2f(p2 & 0xFFFFu) * g2 + bu2f(p3 & 0xFFFFu) * g3;
        acc += bu2f(p4 & 0xFFFFu) * g4 + bu2f(p5 & 0xFFFFu) * g5 +
               bu2f(p6 & 0xFFFFu) * g6 + bu2f(p7 & 0xFFFFu) * g7;
    }
    for (; j < e; ++j) {
        unsigned p = pairs4[j];
        acc += bu2f(p & 0xFFFFu) * bu2f(txo[(p >> 16) * 64 + lane]);
    }
    int o = wv * 64 + lane;
    float c0 = coeffs[0], c1 = coeffs[1], c2 = coeffs[2],
          c3 = coeffs[3], c4 = coeffs[4], c5 = coeffs[5];
    float v = (1.f + c0) * h[o] + c1 * bu2f(t1[o]) + c2 * bu2f(t2[o]) +
              c3 * bu2f(t3[o]) + c4 * bu2f(t4[o]) + c5 * acc;
    float m = v;
    for (int off = 1; off < 64; off <<= 1) m += __shfl_xor(m, off, 64);
    m *= (1.f / 64.f);
    float d = v - m;
    float q = d * d;
    for (int off = 1; off < 64; off <<= 1) q += __shfl_xor(q, off, 64);
    float var = q * (1.f / 64.f);
    float y = d / sqrtf(var + 1e-5f) * sc[layer * 64 + lane] + bi[layer * 64 + lane];
    h[o] = y;
    h_bf[o] = f2bu(y);
    if (last) {
        if (*flag) ((float*)outv)[N_EDGES + o] = y;
        else       ((unsigned short*)outv)[N_EDGES + o] = f2bu(y);
    }
}

// ---------------- edge predictor ----------------

__global__ void __launch_bounds__(256) k_uv(const float* __restrict__ h,
                                            const float* __restrict__ W1,
                                            unsigned short* __restrict__ ub,
                                            unsigned short* __restrict__ vb) {
    __shared__ float Wt[128 * 65];
    __shared__ float hs[4 * 64];
    int t = threadIdx.x;
    for (int idx = t; idx < 8192; idx += 256) {
        int f = idx >> 7, j = idx & 127;
        Wt[j * 65 + f] = W1[idx];
    }
    int node0 = blockIdx.x * 4;
    hs[t] = h[node0 * 64 + t];
    __syncthreads();
    int ni = t >> 6, f = t & 63;
    const float* hr = hs + ni * 64;
    float au = 0.f, av = 0.f;
#pragma unroll 8
    for (int j = 0; j < 64; ++j) {
        float xv = hr[j];
        au += Wt[j * 65 + f] * xv;
        av += Wt[(j + 64) * 65 + f] * xv;
    }
    int i = node0 + ni;
    ub[i * 64 + f] = f2bu(au);
    vb[i * 64 + f] = f2bu(av);
}

// MFMA edge predictor: 16 CSR-ordered edges per wave-iteration.
__global__ void __launch_bounds__(256) k_edgepred(
    const unsigned short* __restrict__ ub, const unsigned short* __restrict__ vb,
    const int2* __restrict__ pairs8,
    const float* __restrict__ eb1, const float* __restrict__ eW2,
    const float* __restrict__ eb2, const float* __restrict__ eW3,
    const float* __restrict__ eb3,
    void* __restrict__ outv, const int* __restrict__ flag) {
    int t = threadIdx.x;
    int lane = t & 63;
    int m = lane & 15, q = lane >> 4;
    int f32o = *flag;

    short8 B00, B01, B10, B11;
#pragma unroll
    for (int j = 0; j < 8; ++j) {
        B00[j] = (short)f2bu(eW2[(m) * 64      + q * 8 + j]);
        B01[j] = (short)f2bu(eW2[(m) * 64 + 32 + q * 8 + j]);
        B10[j] = (short)f2bu(eW2[(m + 16) * 64      + q * 8 + j]);
        B11[j] = (short)f2bu(eW2[(m + 16) * 64 + 32 + q * 8 + j]);
    }
    float b1f0[8], b1f1[8];
#pragma unroll
    for (int j = 0; j < 8; ++j) {
        b1f0[j] = eb1[q * 8 + j];
        b1f1[j] = eb1[32 + q * 8 + j];
    }
    float w3a = eW3[m], w3b = eW3[16 + m];
    float b2a = eb2[m], b2b = eb2[16 + m];
    float b3v = eb3[0];

    int gw = blockIdx.x * 4 + (t >> 6);
    const int NW = 1563 * 4;
    for (int tile = gw; tile < N_EDGES / 16; tile += NW) {
        int base = tile << 4;
        int2 pm = pairs8[base + m];
        int col = pm.x & 0xFFFF;
        int row = ((unsigned)pm.x) >> 16;
        int eidv = pm.y;
        const unsigned short* up = ub + row * 64;
        const unsigned short* vp = vb + col * 64;
        uint4 U0 = *(const uint4*)(up + q * 8);
        uint4 U1 = *(const uint4*)(up + 32 + q * 8);
        uint4 V0 = *(const uint4*)(vp + q * 8);
        uint4 V1 = *(const uint4*)(vp + 32 + q * 8);
        short8 A0, A1;
        {
            unsigned uu[4] = {U0.x, U0.y, U0.z, U0.w};
            unsigned vv[4] = {V0.x, V0.y, V0.z, V0.w};
#pragma unroll
            for (int w = 0; w < 4; ++w) {
                float e0 = fmaxf(bu2f(uu[w] & 0xFFFFu) + bu2f(vv[w] & 0xFFFFu) + b1f0[2 * w], 0.f);
                float e1 = fmaxf(bu2f(uu[w] >> 16)     + bu2f(vv[w] >> 16)     + b1f0[2 * w + 1], 0.f);
                A0[2 * w] = (short)f2bu(e0);
                A0[2 * w + 1] = (short)f2bu(e1);
            }
        }
        {
            unsigned uu[4] = {U1.x, U1.y, U1.z, U1.w};
            unsigned vv[4] = {V1.x, V1.y, V1.z, V1.w};
#pragma unroll
            for (int w = 0; w < 4; ++w) {
                float e0 = fmaxf(bu2f(uu[w] & 0xFFFFu) + bu2f(vv[w] & 0xFFFFu) + b1f1[2 * w], 0.f);
                float e1 = fmaxf(bu2f(uu[w] >> 16)     + bu2f(vv[w] >> 16)     + b1f1[2 * w + 1], 0.f);
                A1[2 * w] = (short)f2bu(e0);
                A1[2 * w + 1] = (short)f2bu(e1);
            }
        }
        f32x4 acc0 = {0.f, 0.f, 0.f, 0.f};
        f32x4 acc1 = {0.f, 0.f, 0.f, 0.f};
        acc0 = __builtin_amdgcn_mfma_f32_16x16x32_bf16(A0, B00, acc0, 0, 0, 0);
        acc0 = __builtin_amdgcn_mfma_f32_16x16x32_bf16(A1, B01, acc0, 0, 0, 0);
        acc1 = __builtin_amdgcn_mfma_f32_16x16x32_bf16(A0, B10, acc1, 0, 0, 0);
        acc1 = __builtin_amdgcn_mfma_f32_16x16x32_bf16(A1, B11, acc1, 0, 0, 0);
        float z[4];
#pragma unroll
        for (int rr = 0; rr < 4; ++rr) {
            z[rr] = w3a * fmaxf(acc0[rr] + b2a, 0.f) + w3b * fmaxf(acc1[rr] + b2b, 0.f);
            z[rr] += __shfl_xor(z[rr], 1, 64);
            z[rr] += __shfl_xor(z[rr], 2, 64);
            z[rr] += __shfl_xor(z[rr], 4, 64);
            z[rr] += __shfl_xor(z[rr], 8, 64);
        }
#pragma unroll
        for (int rr = 0; rr < 4; ++rr) {
            int src = (q << 4) + (q << 2) + rr;
            int eidr = __shfl(eidv, src, 64);
            if (m == 0) {
                float p = 1.f / (1.f + __expf(-(z[rr] + b3v)));
                if (f32o) ((float*)outv)[eidr] = p;
                else      ((unsigned short*)outv)[eidr] = f2bu(p);
            }
        }
    }
}

// ---------------- launch ----------------

extern "C" void kernel_launch(void* const* d_in, const int* in_sizes, int n_in,
                              void* d_out, int out_size, void* d_ws, size_t ws_size,
                              hipStream_t stream) {
    (void)in_sizes; (void)n_in; (void)out_size; (void)ws_size;
    const void* x_r   = d_in[0];
    const int*  ei    = (const int*)d_in[1];
    const void* ew_r  = d_in[2];

    char* w = (char*)d_ws;
    float* h            = (float*)w;          w += (size_t)NH * 4;       // 12.8 MB
    unsigned short* hbf = (unsigned short*)w; w += (size_t)NH * 2;       // 6.4
    char* txr           = w;                  w += (size_t)NH * 8;       // 25.6 (4 bufs)
    unsigned int* pairs4 = (unsigned int*)w;  w += (size_t)N_EDGES * 4;  // 6.4
    int2* pairs8        = (int2*)w;           w += (size_t)N_EDGES * 8;  // 12.8
    int* row_ptr        = (int*)w;            w += 200192;
    int* base8          = (int*)w;            w += (size_t)8 * XSTRIDE * 4;  // 1.6 MB
    int* cnt            = (int*)w;            w += 200192;
    float* dis          = (float*)w;          w += 200192;
    float* cWin = (float*)w; w += 2048;
    float* cbin = (float*)w; w += 256;
    float* ccW1 = (float*)w; w += 26112;
    float* ccb1 = (float*)w; w += 384;
    float* ccW2 = (float*)w; w += 2304;
    float* ccb2 = (float*)w; w += 128;
    float* clns = (float*)w; w += 768;
    float* clnb = (float*)w; w += 768;
    float* ceW1 = (float*)w; w += 32768;
    float* ceb1 = (float*)w; w += 256;
    float* ceW2 = (float*)w; w += 8192;
    float* ceb2 = (float*)w; w += 128;
    float* ceW3 = (float*)w; w += 128;
    float* ceb3 = (float*)w; w += 128;
    char* zero_base = w;
    int*   cnt8 = (int*)w;   w += (size_t)8 * XSTRIDE * 4;   // 1.6 MB (zeroed)
    float* deg8 = (float*)w; w += (size_t)8 * XSTRIDE * 4;   // 1.6 MB (zeroed)
    float* stats = (float*)w; w += 1024;
    size_t zero_bytes = (size_t)(w - zero_base);
    float* coeffs = (float*)w; w += 128;
    int*   flag   = (int*)w;   w += 128;

    unsigned short* tx[4];
    for (int k = 0; k < 4; ++k) tx[k] = (unsigned short*)txr + (size_t)k * NH;
    unsigned short* ub = tx[0];   // k_uv runs after last spmm_ln: tx dead
    unsigned short* vb = tx[1];

    hipMemsetAsync(zero_base, 0, zero_bytes, stream);

    k_detect<<<1, 64, 0, stream>>>(ew_r, flag);

    ConvArgs ca;
    const void* srcs[14] = {d_in[3], d_in[4], d_in[5], d_in[6], d_in[7], d_in[8], d_in[9],
                            d_in[10], d_in[11], d_in[12], d_in[13], d_in[14], d_in[15], d_in[16]};
    float* dsts[14] = {cWin, cbin, ccW1, ccb1, ccW2, ccb2, clns,
                       clnb, ceW1, ceb1, ceW2, ceb2, ceW3, ceb3};
    int sizes[14] = {512, 64, 6528, 96, 576, 18, 192, 192, 8192, 64, 2048, 32, 32, 1};
    int c = 0;
    for (int i = 0; i < 14; ++i) { ca.src[i] = srcs[i]; ca.dst[i] = dsts[i]; ca.cum[i] = c; c += sizes[i]; }
    ca.cum[14] = c;
    k_conv_small<<<(c + 255) / 256, 256, 0, stream>>>(ca, flag);

    {
        void* args[] = {(void*)&ei, (void*)&ew_r, (void*)&flag, (void*)&cnt8, (void*)&deg8,
                        (void*)&cnt, (void*)&dis, (void*)&row_ptr, (void*)&base8,
                        (void*)&pairs4, (void*)&pairs8};
        hipLaunchCooperativeKernel((const void*)k_csr, dim3(CSR_BLOCKS), dim3(256),
                                   args, 0, stream);
    }

    k_inproj<<<12500, 256, 0, stream>>>(x_r, cWin, cbin, h, hbf, flag);

    for (int l = 0; l < NLAYERS; ++l) {
        k_stats<<<400, 256, 0, stream>>>(h, stats + l * 80);
        k_coeffs<<<1, 64, 0, stream>>>(stats + l * 80, ccW1, ccb1, ccW2, ccb2, l,
                                       coeffs + l * 8);
        const unsigned short* src = hbf;
        for (int k = 0; k < 4; ++k) {
            k_spmm<<<12500, 256, 0, stream>>>(src, tx[k], row_ptr, pairs4);
            src = tx[k];
        }
        k_spmm_ln<<<12500, 256, 0, stream>>>(tx[3], row_ptr, pairs4, h, hbf,
                                             tx[0], tx[1], tx[2], tx[3],
                                             coeffs + l * 8, clns, clnb, l,
                                             (l == NLAYERS - 1) ? 1 : 0, d_out, flag);
    }

    k_uv<<<12500, 256, 0, stream>>>(h, ceW1, ub, vb);
    k_edgepred<<<1563, 256, 0, stream>>>(ub, vb, pairs8, ceb1, ceW2, ceb2, ceW3, ceb3,
                                         d_out, flag);
}

// Round 7
// 1148.650 us; speedup vs baseline: 1.2217x; 1.2217x over previous
//
#include <hip/hip_runtime.h>
#include <hip/hip_bf16.h>

typedef __hip_bfloat16 bf16;
typedef __attribute__((ext_vector_type(8))) short short8;
typedef __attribute__((ext_vector_type(4))) float f32x4;

#define N_NODES 50000
#define N_EDGES 1600000
#define FIN 8
#define HD 64
#define NH (N_NODES * HD)
#define NLAYERS 3

// CSR build geometry
#define NSLC 128                  // row-count slices, E/NSLC = 12500
#define ESLC (N_EDGES / NSLC)
#define NSLD 32                   // degree slices, E/NSLD = 50000
#define ESLD (N_EDGES / NSLD)
#define SUBSZ 16384               // nodes per subrange (r>>14)
#define NSUB 4

__device__ __forceinline__ float b2f(bf16 v) { return __bfloat162float(v); }
__device__ __forceinline__ float bu2f(unsigned int u) { return __uint_as_float(u << 16); }
__device__ __forceinline__ unsigned short f2bu(float f) {
    unsigned int x = __float_as_uint(f);
    unsigned int r = x + 0x7FFFu + ((x >> 16) & 1u);
    return (unsigned short)(r >> 16);
}

// ---------------- dtype detection ----------------
__global__ void k_detect(const void* __restrict__ ew, int* __restrict__ flag) {
    int ok = 1;
    for (int i = threadIdx.x; i < 512; i += 64) {
        float v = b2f(((const bf16*)ew)[i]);
        if (!(v >= 0.f && v <= 1.f)) ok = 0;
    }
    unsigned long long m = __ballot(ok);
    if (threadIdx.x == 0) *flag = (m == 0xFFFFFFFFFFFFFFFFull) ? 0 : 1;
}

struct ConvArgs {
    const void* src[14];
    float* dst[14];
    int cum[15];
};

__global__ void k_conv_small(ConvArgs a, const int* __restrict__ flag) {
    int q = blockIdx.x * 256 + threadIdx.x;
    if (q >= a.cum[14]) return;
    int s = 0;
    while (q >= a.cum[s + 1]) ++s;
    int off = q - a.cum[s];
    if (*flag) a.dst[s][off] = ((const float*)a.src[s])[off];
    else       a.dst[s][off] = bu2f(((const unsigned short*)a.src[s])[off]);
}

// ---------------- CSR build: LDS-private histograms, no global atomics ----------------
// blocks [0,512): row counts.  sub = b&3, slice = b>>2 (adjacent blocks share edge range -> L2 reuse)
// blocks [512,640): weighted col degrees.
__global__ void __launch_bounds__(256) k_hist(const int* __restrict__ ei,
                                              const void* __restrict__ ewr,
                                              const int* __restrict__ flag,
                                              unsigned short* __restrict__ pcnt16,
                                              float* __restrict__ pdeg) {
    __shared__ int sm[SUBSZ];
    int b = blockIdx.x, t = threadIdx.x;
    if (b < 512) {
        int sub = b & 3, slice = b >> 2;
        for (int i = t; i < SUBSZ; i += 256) sm[i] = 0;
        __syncthreads();
        int ebase = slice * ESLC;
        for (int el = t; el < ESLC; el += 256) {
            int r = ei[ebase + el];
            if ((r >> 14) == sub) atomicAdd(&sm[r & (SUBSZ - 1)], 1);
        }
        __syncthreads();
        int nbase = sub << 14;
        for (int i = t; i < SUBSZ; i += 256) {
            int n = nbase + i;
            if (n < N_NODES) pcnt16[slice * N_NODES + n] = (unsigned short)sm[i];
        }
    } else {
        int idx = b - 512;
        int sub = idx & 3, slice = idx >> 2;
        float* smf = (float*)sm;
        for (int i = t; i < SUBSZ; i += 256) smf[i] = 0.f;
        __syncthreads();
        int f32 = *flag;
        int ebase = slice * ESLD;
        for (int el = t; el < ESLD; el += 256) {
            int e = ebase + el;
            int c = ei[N_EDGES + e];
            if ((c >> 14) == sub) {
                float w = f32 ? ((const float*)ewr)[e] : bu2f(((const unsigned short*)ewr)[e]);
                atomicAdd(&smf[c & (SUBSZ - 1)], w);
            }
        }
        __syncthreads();
        int nbase = sub << 14;
        for (int i = t; i < SUBSZ; i += 256) {
            int n = nbase + i;
            if (n < N_NODES) pdeg[slice * N_NODES + n] = smf[i];
        }
    }
}

// per-node: total count, per-slice u16 prefix, degree sum -> dis
__global__ void k_merge(const unsigned short* __restrict__ pcnt16,
                        const float* __restrict__ pdeg,
                        int* __restrict__ cnt, float* __restrict__ dis,
                        unsigned short* __restrict__ pref16) {
    int n = blockIdx.x * 256 + threadIdx.x;
    if (n >= N_NODES) return;
    int run = 0;
#pragma unroll 8
    for (int s = 0; s < NSLC; ++s) {
        pref16[s * N_NODES + n] = (unsigned short)run;
        run += pcnt16[s * N_NODES + n];
    }
    cnt[n] = run;
    float d = 0.f;
#pragma unroll 8
    for (int s = 0; s < NSLD; ++s) d += pdeg[s * N_NODES + n];
    dis[n] = fminf(rsqrtf(d), 1e6f);   // rsqrt(0)=inf -> 1e6, matches ref clamp
}

// 2-pass scan: per-thread chunk of 49, one 1024-wide Hillis-Steele
__global__ void k_scan(const int* __restrict__ cnt, int* __restrict__ row_ptr) {
    __shared__ int part[1024];
    int t = threadIdx.x;
    const int CH = 49;
    int base = t * CH;
    int s = 0;
    for (int i = 0; i < CH; ++i) {
        int idx = base + i;
        if (idx < N_NODES) s += cnt[idx];
    }
    part[t] = s;
    __syncthreads();
    int val = s;
    for (int off = 1; off < 1024; off <<= 1) {
        int other = (t >= off) ? part[t - off] : 0;
        __syncthreads();
        val += other;
        part[t] = val;
        __syncthreads();
    }
    int run = val - s;
    for (int i = 0; i < CH; ++i) {
        int idx = base + i;
        if (idx <= N_NODES) row_ptr[idx] = run;
        if (idx < N_NODES) run += cnt[idx];
    }
}

// placement A: LDS offsets, scatter only perm[pos]=e (4 B payload)
__global__ void __launch_bounds__(256) k_placeA(const int* __restrict__ ei,
                                                const int* __restrict__ row_ptr,
                                                const unsigned short* __restrict__ pref16,
                                                int* __restrict__ perm) {
    __shared__ int off[SUBSZ];
    int b = blockIdx.x, t = threadIdx.x;
    int sub = b & 3, slice = b >> 2;
    int nbase = sub << 14;
    for (int i = t; i < SUBSZ; i += 256) {
        int n = nbase + i;
        off[i] = (n < N_NODES) ? row_ptr[n] + pref16[slice * N_NODES + n] : 0;
    }
    __syncthreads();
    int ebase = slice * ESLC;
    for (int el = t; el < ESLC; el += 256) {
        int e = ebase + el;
        int r = ei[e];
        if ((r >> 14) == sub) {
            int pos = atomicAdd(&off[r & (SUBSZ - 1)], 1);
            perm[pos] = e;
        }
    }
}

// placement B: coalesced expansion of perm into pairs4/pairs8
__global__ void k_placeB(const int* __restrict__ ei, const void* __restrict__ ewr,
                         const float* __restrict__ dis, const int* __restrict__ perm,
                         const int* __restrict__ flag,
                         unsigned int* __restrict__ pairs4, int2* __restrict__ pairs8) {
    int pos = blockIdx.x * 256 + threadIdx.x;
    if (pos >= N_EDGES) return;
    int e = perm[pos];
    int r = ei[e], c = ei[N_EDGES + e];
    float w = (*flag) ? ((const float*)ewr)[e] : bu2f(((const unsigned short*)ewr)[e]);
    float nrm = dis[r] * w * dis[c];
    pairs4[pos] = ((unsigned)c << 16) | (unsigned)f2bu(nrm);
    int2 p8;
    p8.x = c | (r << 16);
    p8.y = e;
    pairs8[pos] = p8;
}

// ---------------- input projection (reads raw x with dtype flag) ----------------

__global__ void k_inproj(const void* __restrict__ xr_, const float* __restrict__ W,
                         const float* __restrict__ b, float* __restrict__ h,
                         unsigned short* __restrict__ h_bf, const int* __restrict__ flag) {
    __shared__ float Wt[FIN * HD];
    __shared__ float bs[HD];
    int t = threadIdx.x;
    int f32 = *flag;
    for (int idx = t; idx < FIN * HD; idx += 256) {
        int f = idx >> 3, j = idx & 7;
        Wt[j * 64 + f] = W[idx];
    }
    if (t < 64) bs[t] = b[t];
    __syncthreads();
    int gid = blockIdx.x * 256 + t;
    if (gid < NH) {
        int i = gid >> 6, f = gid & 63;
        const float* xf = (const float*)xr_ + i * FIN;
        const unsigned short* xb = (const unsigned short*)xr_ + i * FIN;
        float acc = bs[f];
#pragma unroll
        for (int j = 0; j < FIN; ++j) {
            float xv = f32 ? xf[j] : bu2f(xb[j]);
            acc += xv * Wt[j * 64 + f];
        }
        h[gid] = acc;
        h_bf[gid] = f2bu(acc);
    }
}

// ---------------- stats + coefficient MLP ----------------

__global__ void k_stats(const float* __restrict__ h, float* __restrict__ stats) {
    __shared__ float ssum[256], ssq[256];
    int t = threadIdx.x;
    float ls = 0.f, lq = 0.f;
    for (int idx = blockIdx.x * 256 + t; idx < NH; idx += 102400) {
        float v = h[idx];
        ls += v; lq += v * v;
    }
    ssum[t] = ls; ssq[t] = lq;
    __syncthreads();
    if (t < 64) {
        float a = ssum[t] + ssum[t + 64] + ssum[t + 128] + ssum[t + 192];
        atomicAdd(&stats[t], a);
        float q = ssq[t] + ssq[t + 64] + ssq[t + 128] + ssq[t + 192];
        for (int off = 32; off; off >>= 1) q += __shfl_down(q, off, 64);
        if (t == 0) atomicAdd(&stats[64], q);
    }
}

__global__ void k_coeffs(const float* __restrict__ stats,
                         const float* __restrict__ W1, const float* __restrict__ b1,
                         const float* __restrict__ W2, const float* __restrict__ b2,
                         int layer, float* __restrict__ coeffs) {
    __shared__ float ci[68];
    __shared__ float hid[32];
    __shared__ float lg[6];
    int t = threadIdx.x;
    float sf = stats[t];
    float tot = sf;
    for (int off = 1; off < 64; off <<= 1) tot += __shfl_xor(tot, off, 64);
    ci[t] = sf / (float)N_NODES;
    if (t == 0) {
        float sumsq = stats[64];
        float mean = tot / (float)NH;
        float var = (sumsq - (float)NH * mean * mean) / (float)(NH - 1);
        ci[64] = mean;
        ci[65] = sqrtf(fmaxf(var, 0.f));
        ci[66] = (float)N_NODES;
        ci[67] = (float)N_EDGES;
    }
    __syncthreads();
    if (t < 32) {
        float a = b1[layer * 32 + t];
        const float* wr = W1 + (layer * 32 + t) * 68;
        for (int j = 0; j < 68; ++j) a += ci[j] * wr[j];
        hid[t] = fmaxf(a, 0.f);
    }
    __syncthreads();
    if (t < 6) {
        float a = b2[layer * 6 + t];
        const float* wr = W2 + (layer * 6 + t) * 32;
        for (int g = 0; g < 32; ++g) a += hid[g] * wr[g];
        lg[t] = a;
    }
    __syncthreads();
    if (t == 0) {
        float mx = lg[0];
        for (int p = 1; p < 6; ++p) mx = fmaxf(mx, lg[p]);
        float s = 0.f, e[6];
        for (int p = 0; p < 6; ++p) { e[p] = expf(lg[p] - mx); s += e[p]; }
        for (int p = 0; p < 6; ++p) coeffs[p] = e[p] / s;
    }
}

// ---------------- SpMM hop: wave per node, lane = feature, 4 B/edge ----------------

__global__ void __launch_bounds__(256) k_spmm(
    const unsigned short* __restrict__ txo, unsigned short* __restrict__ txn,
    const int* __restrict__ row_ptr, const unsigned int* __restrict__ pairs4) {
    int lane = threadIdx.x & 63;
    int wv = __builtin_amdgcn_readfirstlane((int)(blockIdx.x * 4 + (threadIdx.x >> 6)));
    int s = __builtin_amdgcn_readfirstlane(row_ptr[wv]);
    int e = __builtin_amdgcn_readfirstlane(row_ptr[wv + 1]);
    float acc = 0.f;
    int j = s;
    for (; j + 7 < e; j += 8) {
        unsigned p0 = pairs4[j],     p1 = pairs4[j + 1], p2 = pairs4[j + 2], p3 = pairs4[j + 3];
        unsigned p4 = pairs4[j + 4], p5 = pairs4[j + 5], p6 = pairs4[j + 6], p7 = pairs4[j + 7];
        float g0 = bu2f(txo[(p0 >> 16) * 64 + lane]);
        float g1 = bu2f(txo[(p1 >> 16) * 64 + lane]);
        float g2 = bu2f(txo[(p2 >> 16) * 64 + lane]);
        float g3 = bu2f(txo[(p3 >> 16) * 64 + lane]);
        float g4 = bu2f(txo[(p4 >> 16) * 64 + lane]);
        float g5 = bu2f(txo[(p5 >> 16) * 64 + lane]);
        float g6 = bu2f(txo[(p6 >> 16) * 64 + lane]);
        float g7 = bu2f(txo[(p7 >> 16) * 64 + lane]);
        acc += bu2f(p0 & 0xFFFFu) * g0 + bu2f(p1 & 0xFFFFu) * g1 +
               bu2f(p2 & 0xFFFFu) * g2 + bu2f(p3 & 0xFFFFu) * g3;
        acc += bu2f(p4 & 0xFFFFu) * g4 + bu2f(p5 & 0xFFFFu) * g5 +
               bu2f(p6 & 0xFFFFu) * g6 + bu2f(p7 & 0xFFFFu) * g7;
    }
    for (; j < e; ++j) {
        unsigned p = pairs4[j];
        acc += bu2f(p & 0xFFFFu) * bu2f(txo[(p >> 16) * 64 + lane]);
    }
    txn[wv * 64 + lane] = f2bu(acc);
}

// ---------------- fused last hop + polynomial combine + layernorm ----------------

__global__ void __launch_bounds__(256) k_spmm_ln(
    const unsigned short* __restrict__ txo,
    const int* __restrict__ row_ptr, const unsigned int* __restrict__ pairs4,
    float* __restrict__ h, unsigned short* __restrict__ h_bf,
    const unsigned short* __restrict__ t1, const unsigned short* __restrict__ t2,
    const unsigned short* __restrict__ t3, const unsigned short* __restrict__ t4,
    const float* __restrict__ coeffs,
    const float* __restrict__ sc, const float* __restrict__ bi,
    int layer, int last, void* __restrict__ outv, const int* __restrict__ flag) {
    int lane = threadIdx.x & 63;
    int wv = __builtin_amdgcn_readfirstlane((int)(blockIdx.x * 4 + (threadIdx.x >> 6)));
    int s = __builtin_amdgcn_readfirstlane(row_ptr[wv]);
    int e = __builtin_amdgcn_readfirstlane(row_ptr[wv + 1]);
    float acc = 0.f;
    int j = s;
    for (; j + 7 < e; j += 8) {
        unsigned p0 = pairs4[j],     p1 = pairs4[j + 1], p2 = pairs4[j + 2], p3 = pairs4[j + 3];
        unsigned p4 = pairs4[j + 4], p5 = pairs4[j + 5], p6 = pairs4[j + 6], p7 = pairs4[j + 7];
        float g0 = bu2f(txo[(p0 >> 16) * 64 + lane]);
        float g1 = bu2f(txo[(p1 >> 16) * 64 + lane]);
        float g2 = bu2f(txo[(p2 >> 16) * 64 + lane]);
        float g3 = bu2f(txo[(p3 >> 16) * 64 + lane]);
        float g4 = bu2f(txo[(p4 >> 16) * 64 + lane]);
        float g5 = bu2f(txo[(p5 >> 16) * 64 + lane]);
        float g6 = bu2f(txo[(p6 >> 16) * 64 + lane]);
        float g7 = bu2f(txo[(p7 >> 16) * 64 + lane]);
        acc += bu2f(p0 & 0xFFFFu) * g0 + bu2f(p1 & 0xFFFFu) * g1 +
               bu2f(p2 & 0xFFFFu) * g2 + bu2f(p3 & 0xFFFFu) * g3;
        acc += bu2f(p4 & 0xFFFFu) * g4 + bu2f(p5 & 0xFFFFu) * g5 +
               bu2f(p6 & 0xFFFFu) * g6 + bu2f(p7 & 0xFFFFu) * g7;
    }
    for (; j < e; ++j) {
        unsigned p = pairs4[j];
        acc += bu2f(p & 0xFFFFu) * bu2f(txo[(p >> 16) * 64 + lane]);
    }
    int o = wv * 64 + lane;
    float c0 = coeffs[0], c1 = coeffs[1], c2 = coeffs[2],
          c3 = coeffs[3], c4 = coeffs[4], c5 = coeffs[5];
    float v = (1.f + c0) * h[o] + c1 * bu2f(t1[o]) + c2 * bu2f(t2[o]) +
              c3 * bu2f(t3[o]) + c4 * bu2f(t4[o]) + c5 * acc;
    float m = v;
    for (int off = 1; off < 64; off <<= 1) m += __shfl_xor(m, off, 64);
    m *= (1.f / 64.f);
    float d = v - m;
    float q = d * d;
    for (int off = 1; off < 64; off <<= 1) q += __shfl_xor(q, off, 64);
    float var = q * (1.f / 64.f);
    float y = d / sqrtf(var + 1e-5f) * sc[layer * 64 + lane] + bi[layer * 64 + lane];
    h[o] = y;
    h_bf[o] = f2bu(y);
    if (last) {
        if (*flag) ((float*)outv)[N_EDGES + o] = y;
        else       ((unsigned short*)outv)[N_EDGES + o] = f2bu(y);
    }
}

// ---------------- edge predictor ----------------

__global__ void __launch_bounds__(256) k_uv(const float* __restrict__ h,
                                            const float* __restrict__ W1,
                                            unsigned short* __restrict__ ub,
                                            unsigned short* __restrict__ vb) {
    __shared__ float Wt[128 * 65];
    __shared__ float hs[4 * 64];
    int t = threadIdx.x;
    for (int idx = t; idx < 8192; idx += 256) {
        int f = idx >> 7, j = idx & 127;
        Wt[j * 65 + f] = W1[idx];
    }
    int node0 = blockIdx.x * 4;
    hs[t] = h[node0 * 64 + t];
    __syncthreads();
    int ni = t >> 6, f = t & 63;
    const float* hr = hs + ni * 64;
    float au = 0.f, av = 0.f;
#pragma unroll 8
    for (int j = 0; j < 64; ++j) {
        float xv = hr[j];
        au += Wt[j * 65 + f] * xv;
        av += Wt[(j + 64) * 65 + f] * xv;
    }
    int i = node0 + ni;
    ub[i * 64 + f] = f2bu(au);
    vb[i * 64 + f] = f2bu(av);
}

// MFMA edge predictor: 16 CSR-ordered edges per wave-iteration.
__global__ void __launch_bounds__(256) k_edgepred(
    const unsigned short* __restrict__ ub, const unsigned short* __restrict__ vb,
    const int2* __restrict__ pairs8,
    const float* __restrict__ eb1, const float* __restrict__ eW2,
    const float* __restrict__ eb2, const float* __restrict__ eW3,
    const float* __restrict__ eb3,
    void* __restrict__ outv, const int* __restrict__ flag) {
    int t = threadIdx.x;
    int lane = t & 63;
    int m = lane & 15, q = lane >> 4;
    int f32o = *flag;

    short8 B00, B01, B10, B11;
#pragma unroll
    for (int j = 0; j < 8; ++j) {
        B00[j] = (short)f2bu(eW2[(m) * 64      + q * 8 + j]);
        B01[j] = (short)f2bu(eW2[(m) * 64 + 32 + q * 8 + j]);
        B10[j] = (short)f2bu(eW2[(m + 16) * 64      + q * 8 + j]);
        B11[j] = (short)f2bu(eW2[(m + 16) * 64 + 32 + q * 8 + j]);
    }
    float b1f0[8], b1f1[8];
#pragma unroll
    for (int j = 0; j < 8; ++j) {
        b1f0[j] = eb1[q * 8 + j];
        b1f1[j] = eb1[32 + q * 8 + j];
    }
    float w3a = eW3[m], w3b = eW3[16 + m];
    float b2a = eb2[m], b2b = eb2[16 + m];
    float b3v = eb3[0];

    int gw = blockIdx.x * 4 + (t >> 6);
    const int NW = 1563 * 4;
    for (int tile = gw; tile < N_EDGES / 16; tile += NW) {
        int base = tile << 4;
        int2 pm = pairs8[base + m];
        int col = pm.x & 0xFFFF;
        int row = ((unsigned)pm.x) >> 16;
        int eidv = pm.y;
        const unsigned short* up = ub + row * 64;
        const unsigned short* vp = vb + col * 64;
        uint4 U0 = *(const uint4*)(up + q * 8);
        uint4 U1 = *(const uint4*)(up + 32 + q * 8);
        uint4 V0 = *(const uint4*)(vp + q * 8);
        uint4 V1 = *(const uint4*)(vp + 32 + q * 8);
        short8 A0, A1;
        {
            unsigned uu[4] = {U0.x, U0.y, U0.z, U0.w};
            unsigned vv[4] = {V0.x, V0.y, V0.z, V0.w};
#pragma unroll
            for (int w = 0; w < 4; ++w) {
                float e0 = fmaxf(bu2f(uu[w] & 0xFFFFu) + bu2f(vv[w] & 0xFFFFu) + b1f0[2 * w], 0.f);
                float e1 = fmaxf(bu2f(uu[w] >> 16)     + bu2f(vv[w] >> 16)     + b1f0[2 * w + 1], 0.f);
                A0[2 * w] = (short)f2bu(e0);
                A0[2 * w + 1] = (short)f2bu(e1);
            }
        }
        {
            unsigned uu[4] = {U1.x, U1.y, U1.z, U1.w};
            unsigned vv[4] = {V1.x, V1.y, V1.z, V1.w};
#pragma unroll
            for (int w = 0; w < 4; ++w) {
                float e0 = fmaxf(bu2f(uu[w] & 0xFFFFu) + bu2f(vv[w] & 0xFFFFu) + b1f1[2 * w], 0.f);
                float e1 = fmaxf(bu2f(uu[w] >> 16)     + bu2f(vv[w] >> 16)     + b1f1[2 * w + 1], 0.f);
                A1[2 * w] = (short)f2bu(e0);
                A1[2 * w + 1] = (short)f2bu(e1);
            }
        }
        f32x4 acc0 = {0.f, 0.f, 0.f, 0.f};
        f32x4 acc1 = {0.f, 0.f, 0.f, 0.f};
        acc0 = __builtin_amdgcn_mfma_f32_16x16x32_bf16(A0, B00, acc0, 0, 0, 0);
        acc0 = __builtin_amdgcn_mfma_f32_16x16x32_bf16(A1, B01, acc0, 0, 0, 0);
        acc1 = __builtin_amdgcn_mfma_f32_16x16x32_bf16(A0, B10, acc1, 0, 0, 0);
        acc1 = __builtin_amdgcn_mfma_f32_16x16x32_bf16(A1, B11, acc1, 0, 0, 0);
        float z[4];
#pragma unroll
        for (int rr = 0; rr < 4; ++rr) {
            z[rr] = w3a * fmaxf(acc0[rr] + b2a, 0.f) + w3b * fmaxf(acc1[rr] + b2b, 0.f);
            z[rr] += __shfl_xor(z[rr], 1, 64);
            z[rr] += __shfl_xor(z[rr], 2, 64);
            z[rr] += __shfl_xor(z[rr], 4, 64);
            z[rr] += __shfl_xor(z[rr], 8, 64);
        }
#pragma unroll
        for (int rr = 0; rr < 4; ++rr) {
            int src = (q << 4) + (q << 2) + rr;
            int eidr = __shfl(eidv, src, 64);
            if (m == 0) {
                float p = 1.f / (1.f + __expf(-(z[rr] + b3v)));
                if (f32o) ((float*)outv)[eidr] = p;
                else      ((unsigned short*)outv)[eidr] = f2bu(p);
            }
        }
    }
}

// ---------------- launch ----------------

extern "C" void kernel_launch(void* const* d_in, const int* in_sizes, int n_in,
                              void* d_out, int out_size, void* d_ws, size_t ws_size,
                              hipStream_t stream) {
    (void)in_sizes; (void)n_in; (void)out_size; (void)ws_size;
    const void* x_r   = d_in[0];
    const int*  ei    = (const int*)d_in[1];
    const void* ew_r  = d_in[2];

    char* w = (char*)d_ws;
    float* h            = (float*)w;          w += (size_t)NH * 4;       // 12.8 MB
    unsigned short* hbf = (unsigned short*)w; w += (size_t)NH * 2;       // 6.4
    char* txr           = w;                  w += (size_t)NH * 8;       // 25.6 (4 bufs)
    unsigned int* pairs4 = (unsigned int*)w;  w += (size_t)N_EDGES * 4;  // 6.4
    int2* pairs8        = (int2*)w;           w += (size_t)N_EDGES * 8;  // 12.8
    int* row_ptr        = (int*)w;            w += 200192;
    int* cnt            = (int*)w;            w += 200192;
    float* dis          = (float*)w;          w += 200192;
    float* cWin = (float*)w; w += 2048;
    float* cbin = (float*)w; w += 256;
    float* ccW1 = (float*)w; w += 26112;
    float* ccb1 = (float*)w; w += 384;
    float* ccW2 = (float*)w; w += 2304;
    float* ccb2 = (float*)w; w += 128;
    float* clns = (float*)w; w += 768;
    float* clnb = (float*)w; w += 768;
    float* ceW1 = (float*)w; w += 32768;
    float* ceb1 = (float*)w; w += 256;
    float* ceW2 = (float*)w; w += 8192;
    float* ceb2 = (float*)w; w += 128;
    float* ceW3 = (float*)w; w += 128;
    float* ceb3 = (float*)w; w += 128;
    char* zero_base = w;
    float* stats = (float*)w; w += 1024;
    size_t zero_bytes = (size_t)(w - zero_base);
    float* coeffs = (float*)w; w += 128;
    int*   flag   = (int*)w;   w += 128;

    // setup-phase overlays (all dead before first hop):
    //  pcnt16 (12.8 MB)  -> pairs8 region   [hist -> merge]
    //  pref16 (12.8 MB)  -> txr + 0         [merge -> placeA]
    //  pdeg   (6.4 MB)   -> txr + 12.8 MB   [hist -> merge]
    //  perm   (6.4 MB)   -> txr + 19.2 MB   [placeA -> placeB]
    unsigned short* pcnt16 = (unsigned short*)pairs8;
    unsigned short* pref16 = (unsigned short*)txr;
    float* pdeg = (float*)(txr + (size_t)N_EDGES * 8);
    int*   perm = (int*)(txr + (size_t)N_EDGES * 12);

    unsigned short* tx[4];
    for (int k = 0; k < 4; ++k) tx[k] = (unsigned short*)txr + (size_t)k * NH;
    unsigned short* ub = tx[0];   // k_uv runs after last spmm_ln: tx dead
    unsigned short* vb = tx[1];

    hipMemsetAsync(zero_base, 0, zero_bytes, stream);

    k_detect<<<1, 64, 0, stream>>>(ew_r, flag);

    ConvArgs ca;
    const void* srcs[14] = {d_in[3], d_in[4], d_in[5], d_in[6], d_in[7], d_in[8], d_in[9],
                            d_in[10], d_in[11], d_in[12], d_in[13], d_in[14], d_in[15], d_in[16]};
    float* dsts[14] = {cWin, cbin, ccW1, ccb1, ccW2, ccb2, clns,
                       clnb, ceW1, ceb1, ceW2, ceb2, ceW3, ceb3};
    int sizes[14] = {512, 64, 6528, 96, 576, 18, 192, 192, 8192, 64, 2048, 32, 32, 1};
    int c = 0;
    for (int i = 0; i < 14; ++i) { ca.src[i] = srcs[i]; ca.dst[i] = dsts[i]; ca.cum[i] = c; c += sizes[i]; }
    ca.cum[14] = c;
    k_conv_small<<<(c + 255) / 256, 256, 0, stream>>>(ca, flag);

    k_hist<<<640, 256, 0, stream>>>(ei, ew_r, flag, pcnt16, pdeg);
    k_merge<<<196, 256, 0, stream>>>(pcnt16, pdeg, cnt, dis, pref16);
    k_scan<<<1, 1024, 0, stream>>>(cnt, row_ptr);
    k_placeA<<<512, 256, 0, stream>>>(ei, row_ptr, pref16, perm);
    k_placeB<<<6250, 256, 0, stream>>>(ei, ew_r, dis, perm, flag, pairs4, pairs8);
    k_inproj<<<12500, 256, 0, stream>>>(x_r, cWin, cbin, h, hbf, flag);

    for (int l = 0; l < NLAYERS; ++l) {
        k_stats<<<400, 256, 0, stream>>>(h, stats + l * 80);
        k_coeffs<<<1, 64, 0, stream>>>(stats + l * 80, ccW1, ccb1, ccW2, ccb2, l,
                                       coeffs + l * 8);
        const unsigned short* src = hbf;
        for (int k = 0; k < 4; ++k) {
            k_spmm<<<12500, 256, 0, stream>>>(src, tx[k], row_ptr, pairs4);
            src = tx[k];
        }
        k_spmm_ln<<<12500, 256, 0, stream>>>(tx[3], row_ptr, pairs4, h, hbf,
                                             tx[0], tx[1], tx[2], tx[3],
                                             coeffs + l * 8, clns, clnb, l,
                                             (l == NLAYERS - 1) ? 1 : 0, d_out, flag);
    }

    k_uv<<<12500, 256, 0, stream>>>(h, ceW1, ub, vb);
    k_edgepred<<<1563, 256, 0, stream>>>(ub, vb, pairs8, ceb1, ceW2, ceb2, ceW3, ceb3,
                                         d_out, flag);
}

// Round 8
// 1074.322 us; speedup vs baseline: 1.3062x; 1.0692x over previous
//
#include <hip/hip_runtime.h>
#include <hip/hip_bf16.h>

typedef __hip_bfloat16 bf16;
typedef __attribute__((ext_vector_type(8))) short short8;
typedef __attribute__((ext_vector_type(4))) float f32x4;

#define N_NODES 50000
#define N_EDGES 1600000
#define FIN 8
#define HD 64
#define NH (N_NODES * HD)
#define NLAYERS 3

// CSR build geometry
#define RSLC 256                 // row slices, E/RSLC = 6250
#define EPR (N_EDGES / RSLC)     // 6250 edges per row-slice
#define NWORDS 12500             // 50000 nodes as packed u8 in u32
#define DSLC 64                  // degree slices, E/DSLC = 25000
#define EPD (N_EDGES / DSLC)
#define DSUB 8192                // degree subrange size
#define NDSUB 7                  // ceil(50000/8192)

__device__ __forceinline__ float b2f(bf16 v) { return __bfloat162float(v); }
__device__ __forceinline__ float bu2f(unsigned int u) { return __uint_as_float(u << 16); }
__device__ __forceinline__ unsigned short f2bu(float f) {
    unsigned int x = __float_as_uint(f);
    unsigned int r = x + 0x7FFFu + ((x >> 16) & 1u);
    return (unsigned short)(r >> 16);
}

// ---------------- dtype detection ----------------
__global__ void k_detect(const void* __restrict__ ew, int* __restrict__ flag) {
    int ok = 1;
    for (int i = threadIdx.x; i < 512; i += 64) {
        float v = b2f(((const bf16*)ew)[i]);
        if (!(v >= 0.f && v <= 1.f)) ok = 0;
    }
    unsigned long long m = __ballot(ok);
    if (threadIdx.x == 0) *flag = (m == 0xFFFFFFFFFFFFFFFFull) ? 0 : 1;
}

struct ConvArgs {
    const void* src[14];
    float* dst[14];
    int cum[15];
};

__global__ void k_conv_small(ConvArgs a, const int* __restrict__ flag) {
    int q = blockIdx.x * 256 + threadIdx.x;
    if (q >= a.cum[14]) return;
    int s = 0;
    while (q >= a.cum[s + 1]) ++s;
    int off = q - a.cum[s];
    if (*flag) a.dst[s][off] = ((const float*)a.src[s])[off];
    else       a.dst[s][off] = bu2f(((const unsigned short*)a.src[s])[off]);
}

// ---------------- CSR build: byte-packed LDS histograms, no global atomics ----------------

// row counts: one block per 6250-edge slice, ALL nodes as u8 packed in u32 (50 KB LDS)
__global__ void __launch_bounds__(256) k_hist_row(const int* __restrict__ ei,
                                                  unsigned int* __restrict__ pcnt_u32) {
    __shared__ unsigned int sm[NWORDS];
    int b = blockIdx.x, t = threadIdx.x;
    for (int i = t; i < NWORDS; i += 256) sm[i] = 0;
    __syncthreads();
    int ebase = b * EPR;
    for (int el = t; el < EPR; el += 256) {
        int r = ei[ebase + el];
        atomicAdd(&sm[r >> 2], 1u << ((r & 3) * 8));
    }
    __syncthreads();
    unsigned int* dst = pcnt_u32 + (size_t)b * NWORDS;
    for (int i = t; i < NWORDS; i += 256) dst[i] = sm[i];
}

// weighted col degrees: (slice, sub) blocks, 32 KB LDS float, slice-major for L2 sharing
__global__ void __launch_bounds__(256) k_hist_deg(const int* __restrict__ ei,
                                                  const void* __restrict__ ewr,
                                                  const int* __restrict__ flag,
                                                  float* __restrict__ pdeg) {
    __shared__ float sm[DSUB];
    int b = blockIdx.x, t = threadIdx.x;
    int slice = b / NDSUB, sub = b % NDSUB;
    for (int i = t; i < DSUB; i += 256) sm[i] = 0.f;
    __syncthreads();
    int f32 = *flag;
    int ebase = slice * EPD;
    for (int el = t; el < EPD; el += 256) {
        int e = ebase + el;
        int c = ei[N_EDGES + e];
        if ((c >> 13) == sub) {
            float w = f32 ? ((const float*)ewr)[e] : bu2f(((const unsigned short*)ewr)[e]);
            atomicAdd(&sm[c & (DSUB - 1)], w);
        }
    }
    __syncthreads();
    int nbase = sub << 13;
    float* dst = pdeg + (size_t)slice * N_NODES;
    for (int i = t; i < DSUB; i += 256) {
        int n = nbase + i;
        if (n < N_NODES) dst[n] = sm[i];
    }
}

// per-node: 256-slice u8 prefix -> pref16, total -> cnt; 64-slice degree sum -> dis
__global__ void k_merge(const unsigned char* __restrict__ pcnt8,
                        const float* __restrict__ pdeg,
                        int* __restrict__ cnt, float* __restrict__ dis,
                        unsigned short* __restrict__ pref16) {
    int n = blockIdx.x * 256 + threadIdx.x;
    if (n >= N_NODES) return;
    int run = 0;
#pragma unroll 8
    for (int s = 0; s < RSLC; ++s) {
        pref16[(size_t)s * N_NODES + n] = (unsigned short)run;
        run += pcnt8[(size_t)s * N_NODES + n];
    }
    cnt[n] = run;
    float d = 0.f;
#pragma unroll 8
    for (int s = 0; s < DSLC; ++s) d += pdeg[(size_t)s * N_NODES + n];
    dis[n] = fminf(rsqrtf(d), 1e6f);   // rsqrt(0)=inf -> 1e6, matches ref clamp
}

// 2-pass scan: per-thread chunk of 49, one 1024-wide Hillis-Steele
__global__ void k_scan(const int* __restrict__ cnt, int* __restrict__ row_ptr) {
    __shared__ int part[1024];
    int t = threadIdx.x;
    const int CH = 49;
    int base = t * CH;
    int s = 0;
    for (int i = 0; i < CH; ++i) {
        int idx = base + i;
        if (idx < N_NODES) s += cnt[idx];
    }
    part[t] = s;
    __syncthreads();
    int val = s;
    for (int off = 1; off < 1024; off <<= 1) {
        int other = (t >= off) ? part[t - off] : 0;
        __syncthreads();
        val += other;
        part[t] = val;
        __syncthreads();
    }
    int run = val - s;
    for (int i = 0; i < CH; ++i) {
        int idx = base + i;
        if (idx <= N_NODES) row_ptr[idx] = run;
        if (idx < N_NODES) run += cnt[idx];
    }
}

// placement A: per-slice u8 ordinal in LDS; pos = row_ptr[r] + pref16[s][r] + ordinal;
// scatter only perm[pos] = e (4 B payload)
__global__ void __launch_bounds__(256) k_placeA(const int* __restrict__ ei,
                                                const int* __restrict__ row_ptr,
                                                const unsigned short* __restrict__ pref16,
                                                int* __restrict__ perm) {
    __shared__ unsigned int sm[NWORDS];
    int b = blockIdx.x, t = threadIdx.x;
    for (int i = t; i < NWORDS; i += 256) sm[i] = 0;
    __syncthreads();
    int ebase = b * EPR;
    const unsigned short* pr = pref16 + (size_t)b * N_NODES;
    for (int el = t; el < EPR; el += 256) {
        int e = ebase + el;
        int r = ei[e];
        int sh = (r & 3) * 8;
        unsigned old = atomicAdd(&sm[r >> 2], 1u << sh);
        int ord = (old >> sh) & 0xFF;
        int pos = row_ptr[r] + pr[r] + ord;
        perm[pos] = e;
    }
}

// placement B: coalesced expansion of perm into pairs4/pairs8
__global__ void k_placeB(const int* __restrict__ ei, const void* __restrict__ ewr,
                         const float* __restrict__ dis, const int* __restrict__ perm,
                         const int* __restrict__ flag,
                         unsigned int* __restrict__ pairs4, int2* __restrict__ pairs8) {
    int pos = blockIdx.x * 256 + threadIdx.x;
    if (pos >= N_EDGES) return;
    int e = perm[pos];
    int r = ei[e], c = ei[N_EDGES + e];
    float w = (*flag) ? ((const float*)ewr)[e] : bu2f(((const unsigned short*)ewr)[e]);
    float nrm = dis[r] * w * dis[c];
    pairs4[pos] = ((unsigned)c << 16) | (unsigned)f2bu(nrm);
    int2 p8;
    p8.x = c | (r << 16);
    p8.y = e;
    pairs8[pos] = p8;
}

// ---------------- input projection (reads raw x with dtype flag) ----------------

__global__ void k_inproj(const void* __restrict__ xr_, const float* __restrict__ W,
                         const float* __restrict__ b, float* __restrict__ h,
                         unsigned short* __restrict__ h_bf, const int* __restrict__ flag) {
    __shared__ float Wt[FIN * HD];
    __shared__ float bs[HD];
    int t = threadIdx.x;
    int f32 = *flag;
    for (int idx = t; idx < FIN * HD; idx += 256) {
        int f = idx >> 3, j = idx & 7;
        Wt[j * 64 + f] = W[idx];
    }
    if (t < 64) bs[t] = b[t];
    __syncthreads();
    int gid = blockIdx.x * 256 + t;
    if (gid < NH) {
        int i = gid >> 6, f = gid & 63;
        const float* xf = (const float*)xr_ + i * FIN;
        const unsigned short* xb = (const unsigned short*)xr_ + i * FIN;
        float acc = bs[f];
#pragma unroll
        for (int j = 0; j < FIN; ++j) {
            float xv = f32 ? xf[j] : bu2f(xb[j]);
            acc += xv * Wt[j * 64 + f];
        }
        h[gid] = acc;
        h_bf[gid] = f2bu(acc);
    }
}

// ---------------- stats + coefficient MLP ----------------

__global__ void k_stats(const float* __restrict__ h, float* __restrict__ stats) {
    __shared__ float ssum[256], ssq[256];
    int t = threadIdx.x;
    float ls = 0.f, lq = 0.f;
    for (int idx = blockIdx.x * 256 + t; idx < NH; idx += 102400) {
        float v = h[idx];
        ls += v; lq += v * v;
    }
    ssum[t] = ls; ssq[t] = lq;
    __syncthreads();
    if (t < 64) {
        float a = ssum[t] + ssum[t + 64] + ssum[t + 128] + ssum[t + 192];
        atomicAdd(&stats[t], a);
        float q = ssq[t] + ssq[t + 64] + ssq[t + 128] + ssq[t + 192];
        for (int off = 32; off; off >>= 1) q += __shfl_down(q, off, 64);
        if (t == 0) atomicAdd(&stats[64], q);
    }
}

__global__ void k_coeffs(const float* __restrict__ stats,
                         const float* __restrict__ W1, const float* __restrict__ b1,
                         const float* __restrict__ W2, const float* __restrict__ b2,
                         int layer, float* __restrict__ coeffs) {
    __shared__ float ci[68];
    __shared__ float hid[32];
    __shared__ float lg[6];
    int t = threadIdx.x;
    float sf = stats[t];
    float tot = sf;
    for (int off = 1; off < 64; off <<= 1) tot += __shfl_xor(tot, off, 64);
    ci[t] = sf / (float)N_NODES;
    if (t == 0) {
        float sumsq = stats[64];
        float mean = tot / (float)NH;
        float var = (sumsq - (float)NH * mean * mean) / (float)(NH - 1);
        ci[64] = mean;
        ci[65] = sqrtf(fmaxf(var, 0.f));
        ci[66] = (float)N_NODES;
        ci[67] = (float)N_EDGES;
    }
    __syncthreads();
    if (t < 32) {
        float a = b1[layer * 32 + t];
        const float* wr = W1 + (layer * 32 + t) * 68;
        for (int j = 0; j < 68; ++j) a += ci[j] * wr[j];
        hid[t] = fmaxf(a, 0.f);
    }
    __syncthreads();
    if (t < 6) {
        float a = b2[layer * 6 + t];
        const float* wr = W2 + (layer * 6 + t) * 32;
        for (int g = 0; g < 32; ++g) a += hid[g] * wr[g];
        lg[t] = a;
    }
    __syncthreads();
    if (t == 0) {
        float mx = lg[0];
        for (int p = 1; p < 6; ++p) mx = fmaxf(mx, lg[p]);
        float s = 0.f, e[6];
        for (int p = 0; p < 6; ++p) { e[p] = expf(lg[p] - mx); s += e[p]; }
        for (int p = 0; p < 6; ++p) coeffs[p] = e[p] / s;
    }
}

// ---------------- SpMM hop: wave per node, lane = feature, 4 B/edge ----------------

__global__ void __launch_bounds__(256) k_spmm(
    const unsigned short* __restrict__ txo, unsigned short* __restrict__ txn,
    const int* __restrict__ row_ptr, const unsigned int* __restrict__ pairs4) {
    int lane = threadIdx.x & 63;
    int wv = __builtin_amdgcn_readfirstlane((int)(blockIdx.x * 4 + (threadIdx.x >> 6)));
    int s = __builtin_amdgcn_readfirstlane(row_ptr[wv]);
    int e = __builtin_amdgcn_readfirstlane(row_ptr[wv + 1]);
    float acc = 0.f;
    int j = s;
    for (; j + 7 < e; j += 8) {
        unsigned p0 = pairs4[j],     p1 = pairs4[j + 1], p2 = pairs4[j + 2], p3 = pairs4[j + 3];
        unsigned p4 = pairs4[j + 4], p5 = pairs4[j + 5], p6 = pairs4[j + 6], p7 = pairs4[j + 7];
        float g0 = bu2f(txo[(p0 >> 16) * 64 + lane]);
        float g1 = bu2f(txo[(p1 >> 16) * 64 + lane]);
        float g2 = bu2f(txo[(p2 >> 16) * 64 + lane]);
        float g3 = bu2f(txo[(p3 >> 16) * 64 + lane]);
        float g4 = bu2f(txo[(p4 >> 16) * 64 + lane]);
        float g5 = bu2f(txo[(p5 >> 16) * 64 + lane]);
        float g6 = bu2f(txo[(p6 >> 16) * 64 + lane]);
        float g7 = bu2f(txo[(p7 >> 16) * 64 + lane]);
        acc += bu2f(p0 & 0xFFFFu) * g0 + bu2f(p1 & 0xFFFFu) * g1 +
               bu2f(p2 & 0xFFFFu) * g2 + bu2f(p3 & 0xFFFFu) * g3;
        acc += bu2f(p4 & 0xFFFFu) * g4 + bu2f(p5 & 0xFFFFu) * g5 +
               bu2f(p6 & 0xFFFFu) * g6 + bu2f(p7 & 0xFFFFu) * g7;
    }
    for (; j < e; ++j) {
        unsigned p = pairs4[j];
        acc += bu2f(p & 0xFFFFu) * bu2f(txo[(p >> 16) * 64 + lane]);
    }
    txn[wv * 64 + lane] = f2bu(acc);
}

// ---------------- fused last hop + polynomial combine + layernorm ----------------

__global__ void __launch_bounds__(256) k_spmm_ln(
    const unsigned short* __restrict__ txo,
    const int* __restrict__ row_ptr, const unsigned int* __restrict__ pairs4,
    float* __restrict__ h, unsigned short* __restrict__ h_bf,
    const unsigned short* __restrict__ t1, const unsigned short* __restrict__ t2,
    const unsigned short* __restrict__ t3, const unsigned short* __restrict__ t4,
    const float* __restrict__ coeffs,
    const float* __restrict__ sc, const float* __restrict__ bi,
    int layer, int last, void* __restrict__ outv, const int* __restrict__ flag) {
    int lane = threadIdx.x & 63;
    int wv = __builtin_amdgcn_readfirstlane((int)(blockIdx.x * 4 + (threadIdx.x >> 6)));
    int s = __builtin_amdgcn_readfirstlane(row_ptr[wv]);
    int e = __builtin_amdgcn_readfirstlane(row_ptr[wv + 1]);
    float acc = 0.f;
    int j = s;
    for (; j + 7 < e; j += 8) {
        unsigned p0 = pairs4[j],     p1 = pairs4[j + 1], p2 = pairs4[j + 2], p3 = pairs4[j + 3];
        unsigned p4 = pairs4[j + 4], p5 = pairs4[j + 5], p6 = pairs4[j + 6], p7 = pairs4[j + 7];
        float g0 = bu2f(txo[(p0 >> 16) * 64 + lane]);
        float g1 = bu2f(txo[(p1 >> 16) * 64 + lane]);
        float g2 = bu2f(txo[(p2 >> 16) * 64 + lane]);
        float g3 = bu2f(txo[(p3 >> 16) * 64 + lane]);
        float g4 = bu2f(txo[(p4 >> 16) * 64 + lane]);
        float g5 = bu2f(txo[(p5 >> 16) * 64 + lane]);
        float g6 = bu2f(txo[(p6 >> 16) * 64 + lane]);
        float g7 = bu2f(txo[(p7 >> 16) * 64 + lane]);
        acc += bu2f(p0 & 0xFFFFu) * g0 + bu2f(p1 & 0xFFFFu) * g1 +
               bu2f(p2 & 0xFFFFu) * g2 + bu2f(p3 & 0xFFFFu) * g3;
        acc += bu2f(p4 & 0xFFFFu) * g4 + bu2f(p5 & 0xFFFFu) * g5 +
               bu2f(p6 & 0xFFFFu) * g6 + bu2f(p7 & 0xFFFFu) * g7;
    }
    for (; j < e; ++j) {
        unsigned p = pairs4[j];
        acc += bu2f(p & 0xFFFFu) * bu2f(txo[(p >> 16) * 64 + lane]);
    }
    int o = wv * 64 + lane;
    float c0 = coeffs[0], c1 = coeffs[1], c2 = coeffs[2],
          c3 = coeffs[3], c4 = coeffs[4], c5 = coeffs[5];
    float v = (1.f + c0) * h[o] + c1 * bu2f(t1[o]) + c2 * bu2f(t2[o]) +
              c3 * bu2f(t3[o]) + c4 * bu2f(t4[o]) + c5 * acc;
    float m = v;
    for (int off = 1; off < 64; off <<= 1) m += __shfl_xor(m, off, 64);
    m *= (1.f / 64.f);
    float d = v - m;
    float q = d * d;
    for (int off = 1; off < 64; off <<= 1) q += __shfl_xor(q, off, 64);
    float var = q * (1.f / 64.f);
    float y = d / sqrtf(var + 1e-5f) * sc[layer * 64 + lane] + bi[layer * 64 + lane];
    h[o] = y;
    h_bf[o] = f2bu(y);
    if (last) {
        if (*flag) ((float*)outv)[N_EDGES + o] = y;
        else       ((unsigned short*)outv)[N_EDGES + o] = f2bu(y);
    }
}

// ---------------- edge predictor ----------------

__global__ void __launch_bounds__(256) k_uv(const float* __restrict__ h,
                                            const float* __restrict__ W1,
                                            unsigned short* __restrict__ ub,
                                            unsigned short* __restrict__ vb) {
    __shared__ float Wt[128 * 65];
    __shared__ float hs[4 * 64];
    int t = threadIdx.x;
    for (int idx = t; idx < 8192; idx += 256) {
        int f = idx >> 7, j = idx & 127;
        Wt[j * 65 + f] = W1[idx];
    }
    int node0 = blockIdx.x * 4;
    hs[t] = h[node0 * 64 + t];
    __syncthreads();
    int ni = t >> 6, f = t & 63;
    const float* hr = hs + ni * 64;
    float au = 0.f, av = 0.f;
#pragma unroll 8
    for (int j = 0; j < 64; ++j) {
        float xv = hr[j];
        au += Wt[j * 65 + f] * xv;
        av += Wt[(j + 64) * 65 + f] * xv;
    }
    int i = node0 + ni;
    ub[i * 64 + f] = f2bu(au);
    vb[i * 64 + f] = f2bu(av);
}

// MFMA edge predictor: 16 CSR-ordered edges per wave-iteration.
__global__ void __launch_bounds__(256) k_edgepred(
    const unsigned short* __restrict__ ub, const unsigned short* __restrict__ vb,
    const int2* __restrict__ pairs8,
    const float* __restrict__ eb1, const float* __restrict__ eW2,
    const float* __restrict__ eb2, const float* __restrict__ eW3,
    const float* __restrict__ eb3,
    void* __restrict__ outv, const int* __restrict__ flag) {
    int t = threadIdx.x;
    int lane = t & 63;
    int m = lane & 15, q = lane >> 4;
    int f32o = *flag;

    short8 B00, B01, B10, B11;
#pragma unroll
    for (int j = 0; j < 8; ++j) {
        B00[j] = (short)f2bu(eW2[(m) * 64      + q * 8 + j]);
        B01[j] = (short)f2bu(eW2[(m) * 64 + 32 + q * 8 + j]);
        B10[j] = (short)f2bu(eW2[(m + 16) * 64      + q * 8 + j]);
        B11[j] = (short)f2bu(eW2[(m + 16) * 64 + 32 + q * 8 + j]);
    }
    float b1f0[8], b1f1[8];
#pragma unroll
    for (int j = 0; j < 8; ++j) {
        b1f0[j] = eb1[q * 8 + j];
        b1f1[j] = eb1[32 + q * 8 + j];
    }
    float w3a = eW3[m], w3b = eW3[16 + m];
    float b2a = eb2[m], b2b = eb2[16 + m];
    float b3v = eb3[0];

    int gw = blockIdx.x * 4 + (t >> 6);
    const int NW = 1563 * 4;
    for (int tile = gw; tile < N_EDGES / 16; tile += NW) {
        int base = tile << 4;
        int2 pm = pairs8[base + m];
        int col = pm.x & 0xFFFF;
        int row = ((unsigned)pm.x) >> 16;
        int eidv = pm.y;
        const unsigned short* up = ub + row * 64;
        const unsigned short* vp = vb + col * 64;
        uint4 U0 = *(const uint4*)(up + q * 8);
        uint4 U1 = *(const uint4*)(up + 32 + q * 8);
        uint4 V0 = *(const uint4*)(vp + q * 8);
        uint4 V1 = *(const uint4*)(vp + 32 + q * 8);
        short8 A0, A1;
        {
            unsigned uu[4] = {U0.x, U0.y, U0.z, U0.w};
            unsigned vv[4] = {V0.x, V0.y, V0.z, V0.w};
#pragma unroll
            for (int w = 0; w < 4; ++w) {
                float e0 = fmaxf(bu2f(uu[w] & 0xFFFFu) + bu2f(vv[w] & 0xFFFFu) + b1f0[2 * w], 0.f);
                float e1 = fmaxf(bu2f(uu[w] >> 16)     + bu2f(vv[w] >> 16)     + b1f0[2 * w + 1], 0.f);
                A0[2 * w] = (short)f2bu(e0);
                A0[2 * w + 1] = (short)f2bu(e1);
            }
        }
        {
            unsigned uu[4] = {U1.x, U1.y, U1.z, U1.w};
            unsigned vv[4] = {V1.x, V1.y, V1.z, V1.w};
#pragma unroll
            for (int w = 0; w < 4; ++w) {
                float e0 = fmaxf(bu2f(uu[w] & 0xFFFFu) + bu2f(vv[w] & 0xFFFFu) + b1f1[2 * w], 0.f);
                float e1 = fmaxf(bu2f(uu[w] >> 16)     + bu2f(vv[w] >> 16)     + b1f1[2 * w + 1], 0.f);
                A1[2 * w] = (short)f2bu(e0);
                A1[2 * w + 1] = (short)f2bu(e1);
            }
        }
        f32x4 acc0 = {0.f, 0.f, 0.f, 0.f};
        f32x4 acc1 = {0.f, 0.f, 0.f, 0.f};
        acc0 = __builtin_amdgcn_mfma_f32_16x16x32_bf16(A0, B00, acc0, 0, 0, 0);
        acc0 = __builtin_amdgcn_mfma_f32_16x16x32_bf16(A1, B01, acc0, 0, 0, 0);
        acc1 = __builtin_amdgcn_mfma_f32_16x16x32_bf16(A0, B10, acc1, 0, 0, 0);
        acc1 = __builtin_amdgcn_mfma_f32_16x16x32_bf16(A1, B11, acc1, 0, 0, 0);
        float z[4];
#pragma unroll
        for (int rr = 0; rr < 4; ++rr) {
            z[rr] = w3a * fmaxf(acc0[rr] + b2a, 0.f) + w3b * fmaxf(acc1[rr] + b2b, 0.f);
            z[rr] += __shfl_xor(z[rr], 1, 64);
            z[rr] += __shfl_xor(z[rr], 2, 64);
            z[rr] += __shfl_xor(z[rr], 4, 64);
            z[rr] += __shfl_xor(z[rr], 8, 64);
        }
#pragma unroll
        for (int rr = 0; rr < 4; ++rr) {
            int src = (q << 4) + (q << 2) + rr;
            int eidr = __shfl(eidv, src, 64);
            if (m == 0) {
                float p = 1.f / (1.f + __expf(-(z[rr] + b3v)));
                if (f32o) ((float*)outv)[eidr] = p;
                else      ((unsigned short*)outv)[eidr] = f2bu(p);
            }
        }
    }
}

// ---------------- launch ----------------

extern "C" void kernel_launch(void* const* d_in, const int* in_sizes, int n_in,
                              void* d_out, int out_size, void* d_ws, size_t ws_size,
                              hipStream_t stream) {
    (void)in_sizes; (void)n_in; (void)out_size; (void)ws_size;
    const void* x_r   = d_in[0];
    const int*  ei    = (const int*)d_in[1];
    const void* ew_r  = d_in[2];

    char* w = (char*)d_ws;
    float* h            = (float*)w;          w += (size_t)NH * 4;       // 12.8 MB
    unsigned short* hbf = (unsigned short*)w; w += (size_t)NH * 2;       // 6.4
    char* txr           = w;                  w += (size_t)NH * 8;       // 25.6 (4 bufs)
    unsigned int* pairs4 = (unsigned int*)w;  w += (size_t)N_EDGES * 4;  // 6.4
    int2* pairs8        = (int2*)w;           w += (size_t)N_EDGES * 8;  // 12.8
    int* row_ptr        = (int*)w;            w += 200192;
    int* cnt            = (int*)w;            w += 200192;
    float* dis          = (float*)w;          w += 200192;
    float* cWin = (float*)w; w += 2048;
    float* cbin = (float*)w; w += 256;
    float* ccW1 = (float*)w; w += 26112;
    float* ccb1 = (float*)w; w += 384;
    float* ccW2 = (float*)w; w += 2304;
    float* ccb2 = (float*)w; w += 128;
    float* clns = (float*)w; w += 768;
    float* clnb = (float*)w; w += 768;
    float* ceW1 = (float*)w; w += 32768;
    float* ceb1 = (float*)w; w += 256;
    float* ceW2 = (float*)w; w += 8192;
    float* ceb2 = (float*)w; w += 128;
    float* ceW3 = (float*)w; w += 128;
    float* ceb3 = (float*)w; w += 128;
    char* zero_base = w;
    float* stats = (float*)w; w += 1024;
    size_t zero_bytes = (size_t)(w - zero_base);
    float* coeffs = (float*)w; w += 128;
    int*   flag   = (int*)w;   w += 128;

    // setup-phase overlays (all lifetimes disjoint with their hosts):
    //  pcnt8  (12.8 MB, 256 x 50000 u8)  -> pairs8 region [hist_row -> merge/placeA zero? no: merge]
    //  pdeg   (12.8 MB, 64 x 50000 f32)  -> h region      [hist_deg -> merge]
    //  pref16 (25.6 MB, 256 x 50000 u16) -> txr           [merge -> placeA]
    //  perm   (6.4 MB)                   -> hbf region    [placeA -> placeB]
    unsigned int* pcnt_u32 = (unsigned int*)pairs8;
    unsigned char* pcnt8   = (unsigned char*)pairs8;
    float* pdeg            = (float*)h;
    unsigned short* pref16 = (unsigned short*)txr;
    int* perm              = (int*)hbf;

    unsigned short* tx[4];
    for (int k = 0; k < 4; ++k) tx[k] = (unsigned short*)txr + (size_t)k * NH;
    unsigned short* ub = tx[0];   // k_uv runs after last spmm_ln: tx dead
    unsigned short* vb = tx[1];

    hipMemsetAsync(zero_base, 0, zero_bytes, stream);

    k_detect<<<1, 64, 0, stream>>>(ew_r, flag);

    ConvArgs ca;
    const void* srcs[14] = {d_in[3], d_in[4], d_in[5], d_in[6], d_in[7], d_in[8], d_in[9],
                            d_in[10], d_in[11], d_in[12], d_in[13], d_in[14], d_in[15], d_in[16]};
    float* dsts[14] = {cWin, cbin, ccW1, ccb1, ccW2, ccb2, clns,
                       clnb, ceW1, ceb1, ceW2, ceb2, ceW3, ceb3};
    int sizes[14] = {512, 64, 6528, 96, 576, 18, 192, 192, 8192, 64, 2048, 32, 32, 1};
    int c = 0;
    for (int i = 0; i < 14; ++i) { ca.src[i] = srcs[i]; ca.dst[i] = dsts[i]; ca.cum[i] = c; c += sizes[i]; }
    ca.cum[14] = c;
    k_conv_small<<<(c + 255) / 256, 256, 0, stream>>>(ca, flag);

    k_hist_row<<<RSLC, 256, 0, stream>>>(ei, pcnt_u32);
    k_hist_deg<<<DSLC * NDSUB, 256, 0, stream>>>(ei, ew_r, flag, pdeg);
    k_merge<<<196, 256, 0, stream>>>(pcnt8, pdeg, cnt, dis, pref16);
    k_scan<<<1, 1024, 0, stream>>>(cnt, row_ptr);
    k_placeA<<<RSLC, 256, 0, stream>>>(ei, row_ptr, pref16, perm);
    k_placeB<<<6250, 256, 0, stream>>>(ei, ew_r, dis, perm, flag, pairs4, pairs8);
    k_inproj<<<12500, 256, 0, stream>>>(x_r, cWin, cbin, h, hbf, flag);

    for (int l = 0; l < NLAYERS; ++l) {
        k_stats<<<400, 256, 0, stream>>>(h, stats + l * 80);
        k_coeffs<<<1, 64, 0, stream>>>(stats + l * 80, ccW1, ccb1, ccW2, ccb2, l,
                                       coeffs + l * 8);
        const unsigned short* src = hbf;
        for (int k = 0; k < 4; ++k) {
            k_spmm<<<12500, 256, 0, stream>>>(src, tx[k], row_ptr, pairs4);
            src = tx[k];
        }
        k_spmm_ln<<<12500, 256, 0, stream>>>(tx[3], row_ptr, pairs4, h, hbf,
                                             tx[0], tx[1], tx[2], tx[3],
                                             coeffs + l * 8, clns, clnb, l,
                                             (l == NLAYERS - 1) ? 1 : 0, d_out, flag);
    }

    k_uv<<<12500, 256, 0, stream>>>(h, ceW1, ub, vb);
    k_edgepred<<<1563, 256, 0, stream>>>(ub, vb, pairs8, ceb1, ceW2, ceb2, ceW3, ceb3,
                                         d_out, flag);
}